// Round 2
// baseline (454.615 us; speedup 1.0000x reference)
//
#include <hip/hip_runtime.h>
#include <cstdint>
#include <cstddef>

typedef __attribute__((ext_vector_type(8))) short bf16x8;
typedef __attribute__((ext_vector_type(4))) float f32x4;

__device__ __forceinline__ unsigned short f2bf(float f) {
  union { float f; uint32_t u; } v; v.f = f;
  uint32_t r = v.u + 0x7fffu + ((v.u >> 16) & 1u);
  return (unsigned short)(r >> 16);
}
__device__ __forceinline__ float bf2f(unsigned short u) {
  union { uint32_t u; float f; } v; v.u = ((uint32_t)u) << 16;
  return v.f;
}

// Q/K/V/att per-head offsets (elements). Layout per head: [b][s][l][128].
// L = 64>>h, cumL = {0,64,96,112}, off = B*SEG*cumL*128 = 65536*cumL
__device__ __forceinline__ size_t head_off(int h) {
  return (size_t)65536 * ((h == 0) ? 0 : (h == 1) ? 64 : (h == 2) ? 96 : 112);
}

// ---------------- fp32 -> bf16 converts ----------------
__global__ void k_cvt(const float* __restrict__ src, unsigned short* __restrict__ dst, int n4) {
  int i = blockIdx.x * 256 + threadIdx.x;
  if (i < n4) {
    float4 f = ((const float4*)src)[i];
    ushort4 u;
    u.x = f2bf(f.x); u.y = f2bf(f.y); u.z = f2bf(f.z); u.w = f2bf(f.w);
    ((ushort4*)dst)[i] = u;
  }
}

// Concat per head: rows [0:128)=Wq, [128:256)=Wk, [256:384)=Wv  (row-major [j][e], e=1024)
__global__ void k_cvt_w(const float* __restrict__ Wq, const float* __restrict__ Wk,
                        const float* __restrict__ Wv, unsigned short* __restrict__ dst) {
  int row = blockIdx.x;              // h*384 + j, 1536 rows
  int h = row / 384, j = row % 384;
  const float* src = (j < 128) ? (Wq + (size_t)(h * 128 + j) * 1024)
                   : (j < 256) ? (Wk + (size_t)(h * 128 + j - 128) * 1024)
                               : (Wv + (size_t)(h * 128 + j - 256) * 1024);
  int e = threadIdx.x * 4;
  float4 f = *(const float4*)(src + e);
  ushort4 u;
  u.x = f2bf(f.x); u.y = f2bf(f.y); u.z = f2bf(f.z); u.w = f2bf(f.w);
  *(ushort4*)(dst + (size_t)row * 1024 + e) = u;
}

// ---------------- stage 1: QKV projection GEMM ----------------
// grid.x in [0,480): M-tiles (one (b,l) block of 128 s-rows); grid.y in [0,3): Q/K/V
__global__ __launch_bounds__(256) void k_qkv(
    const unsigned short* __restrict__ xbf,
    const unsigned short* __restrict__ wbf,
    unsigned short* __restrict__ qws,
    unsigned short* __restrict__ kws,
    unsigned short* __restrict__ vws) {
  int gx = blockIdx.x, gy = blockIdx.y;
  int h, base;
  if (gx < 256)      { h = 0; base = 0; }
  else if (gx < 384) { h = 1; base = 256; }
  else if (gx < 448) { h = 2; base = 384; }
  else               { h = 3; base = 448; }
  int L = 64 >> h, dil = 1 << h;
  int inner = gx - base;
  int b = inner >> (6 - h);
  int l = inner & (L - 1);
  const unsigned short* Abase = xbf + ((size_t)(b * 8192 + l * dil * 128)) * 1024;
  const unsigned short* Bbase = wbf + ((size_t)(h * 384 + gy * 128)) * 1024;

  __shared__ unsigned short As[128][72];
  __shared__ unsigned short Bs[128][72];

  int tid = threadIdx.x;
  int lane = tid & 63, wave = tid >> 6;
  int wm = wave >> 1, wn = wave & 1;
  int li = lane & 15, lk8 = (lane >> 4) << 3;

  f32x4 acc[4][4] = {};

  int sr = tid >> 1, sc = (tid & 1) * 32;
  const unsigned short* Ag = Abase + (size_t)sr * 1024 + sc;
  const unsigned short* Bg = Bbase + (size_t)sr * 1024 + sc;

  for (int kc = 0; kc < 1024; kc += 64) {
    bf16x8 av[4], bv[4];
#pragma unroll
    for (int i = 0; i < 4; ++i) {
      av[i] = *(const bf16x8*)(Ag + kc + i * 8);
      bv[i] = *(const bf16x8*)(Bg + kc + i * 8);
    }
    __syncthreads();
#pragma unroll
    for (int i = 0; i < 4; ++i) {
      *(bf16x8*)&As[sr][sc + i * 8] = av[i];
      *(bf16x8*)&Bs[sr][sc + i * 8] = bv[i];
    }
    __syncthreads();
#pragma unroll
    for (int kk = 0; kk < 2; ++kk) {
      int k0 = kk * 32 + lk8;
      bf16x8 af[4], bfv[4];
#pragma unroll
      for (int mf = 0; mf < 4; ++mf)
        af[mf] = *(const bf16x8*)&As[wm * 64 + mf * 16 + li][k0];
#pragma unroll
      for (int nf = 0; nf < 4; ++nf)
        bfv[nf] = *(const bf16x8*)&Bs[wn * 64 + nf * 16 + li][k0];
#pragma unroll
      for (int mf = 0; mf < 4; ++mf)
#pragma unroll
        for (int nf = 0; nf < 4; ++nf)
          acc[mf][nf] = __builtin_amdgcn_mfma_f32_16x16x32_bf16(af[mf], bfv[nf], acc[mf][nf], 0, 0, 0);
    }
  }
  unsigned short* dst = ((gy == 0) ? qws : (gy == 1) ? kws : vws) + head_off(h);
  int ib = (lane >> 4) * 4;
#pragma unroll
  for (int mf = 0; mf < 4; ++mf) {
#pragma unroll
    for (int nf = 0; nf < 4; ++nf) {
#pragma unroll
      for (int rg = 0; rg < 4; ++rg) {
        int s = wm * 64 + mf * 16 + ib + rg;
        int j = wn * 64 + nf * 16 + li;
        dst[((size_t)((b * 128 + s) * L + l)) * 128 + j] = f2bf(acc[mf][nf][rg]);
      }
    }
  }
}

// ---------------- stage 2: dilated attention (reference semantics!) ----------------
// softmax over QUERY axis m of KQ[n,m], mask m<=n, att[m,v] = sum_{n>=m} P[n,m] V[n,v]
__global__ __launch_bounds__(256) void k_attn(
    const unsigned short* __restrict__ qws,
    const unsigned short* __restrict__ kws,
    const unsigned short* __restrict__ vws,
    unsigned short* __restrict__ att) {
  int h = blockIdx.y;
  int bs = blockIdx.x;                 // b*128 + s
  int L = 64 >> h;
  size_t off = head_off(h) + (size_t)bs * L * 128;
  const unsigned short* Qg = qws + off;
  const unsigned short* Kg = kws + off;
  const unsigned short* Vg = vws + off;

  __shared__ unsigned short Ks[64 * 128];
  __shared__ unsigned short Q2[64 * 128];   // holds Q, later reused for V
  __shared__ float S[64][65];

  int tid = threadIdx.x;
  int n8 = (L * 128) / 8;
  for (int i = tid; i < n8; i += 256) {
    ((bf16x8*)Ks)[i] = ((const bf16x8*)Kg)[i];
    ((bf16x8*)Q2)[i] = ((const bf16x8*)Qg)[i];
  }
  __syncthreads();
  for (int p = tid; p < L * L; p += 256) {
    int n = p >> (6 - h), m = p & (L - 1);
    if (m <= n) {
      const uint32_t* kr = (const uint32_t*)(Ks + n * 128);
      const uint32_t* qr = (const uint32_t*)(Q2 + m * 128);
      float a = 0.f;
#pragma unroll 8
      for (int d = 0; d < 64; ++d) {
        uint32_t ku = kr[d], qu = qr[d];
        union { uint32_t u; float f; } kl, kh, ql, qh;
        kl.u = ku << 16; kh.u = ku & 0xffff0000u;
        ql.u = qu << 16; qh.u = qu & 0xffff0000u;
        a += kl.f * ql.f + kh.f * qh.f;
      }
      S[n][m] = a * 0.08838834764831845f;   // 1/sqrt(128)
    }
  }
  __syncthreads();
  if (tid < L) {
    int n = tid;
    float mx = -1e30f;
    for (int m = 0; m <= n; ++m) mx = fmaxf(mx, S[n][m]);
    float sum = 0.f;
    for (int m = 0; m <= n; ++m) { float e = __expf(S[n][m] - mx); S[n][m] = e; sum += e; }
    float inv = 1.f / sum;
    for (int m = 0; m <= n; ++m) S[n][m] *= inv;
  }
  __syncthreads();
  for (int i = tid; i < n8; i += 256)     // V over Q2
    ((bf16x8*)Q2)[i] = ((const bf16x8*)Vg)[i];
  __syncthreads();
  for (int o = tid; o < L * 128; o += 256) {
    int m = o >> 7, vv = o & 127;
    float a = 0.f;
    for (int n = m; n < L; ++n)
      a += S[n][m] * bf2f(Q2[n * 128 + vv]);
    att[off + (size_t)m * 128 + vv] = f2bf(a);
  }
}

// ---------------- stage 3: gather + output projection GEMM ----------------
__global__ __launch_bounds__(256) void k_out(
    const unsigned short* __restrict__ att,
    const unsigned short* __restrict__ wout,
    const float* __restrict__ bout,
    float* __restrict__ out) {
  int mt = blockIdx.x, nt = blockIdx.y;
  int row0 = mt * 128;

  __shared__ unsigned short As[128][72];
  __shared__ unsigned short Bs[128][72];

  int tid = threadIdx.x;
  int lane = tid & 63, wave = tid >> 6;
  int wm = wave >> 1, wn = wave & 1;
  int li = lane & 15, lk8 = (lane >> 4) << 3;

  f32x4 acc[4][4] = {};

  int sr = tid >> 1, sc = (tid & 1) * 32;
  int rowg = row0 + sr;
  int b = rowg >> 13, t = rowg & 8191;
  const unsigned short* Bg = wout + (size_t)(nt * 128 + sr) * 512 + sc;
  const bf16x8 ZV = {0, 0, 0, 0, 0, 0, 0, 0};

  for (int kc = 0; kc < 512; kc += 64) {
    int c0 = kc + sc;
    int hd = c0 >> 7, v0 = c0 & 127;
    int dil = 1 << hd, Lh = 64 >> hd;
    bf16x8 av[4], bv[4];
    if ((t & (dil - 1)) == 0) {
      int j = t >> hd;
      int s = j >> (6 - hd), l = j & (Lh - 1);
      const unsigned short* Ag = att + head_off(hd)
          + ((size_t)((b * 128 + s) * Lh + l)) * 128 + v0;
#pragma unroll
      for (int i = 0; i < 4; ++i) av[i] = *(const bf16x8*)(Ag + i * 8);
    } else {
#pragma unroll
      for (int i = 0; i < 4; ++i) av[i] = ZV;
    }
#pragma unroll
    for (int i = 0; i < 4; ++i) bv[i] = *(const bf16x8*)(Bg + kc + i * 8);
    __syncthreads();
#pragma unroll
    for (int i = 0; i < 4; ++i) {
      *(bf16x8*)&As[sr][sc + i * 8] = av[i];
      *(bf16x8*)&Bs[sr][sc + i * 8] = bv[i];
    }
    __syncthreads();
#pragma unroll
    for (int kk = 0; kk < 2; ++kk) {
      int k0 = kk * 32 + lk8;
      bf16x8 af[4], bfv[4];
#pragma unroll
      for (int mf = 0; mf < 4; ++mf)
        af[mf] = *(const bf16x8*)&As[wm * 64 + mf * 16 + li][k0];
#pragma unroll
      for (int nf = 0; nf < 4; ++nf)
        bfv[nf] = *(const bf16x8*)&Bs[wn * 64 + nf * 16 + li][k0];
#pragma unroll
      for (int mf = 0; mf < 4; ++mf)
#pragma unroll
        for (int nf = 0; nf < 4; ++nf)
          acc[mf][nf] = __builtin_amdgcn_mfma_f32_16x16x32_bf16(af[mf], bfv[nf], acc[mf][nf], 0, 0, 0);
    }
  }
  int ib = (lane >> 4) * 4;
#pragma unroll
  for (int mf = 0; mf < 4; ++mf) {
#pragma unroll
    for (int nf = 0; nf < 4; ++nf) {
      int col = nt * 128 + wn * 64 + nf * 16 + li;
      float bo = bout[col];
#pragma unroll
      for (int rg = 0; rg < 4; ++rg) {
        int r = row0 + wm * 64 + mf * 16 + ib + rg;
        out[(size_t)r * 1024 + col] = acc[mf][nf][rg] + bo;
      }
    }
  }
}

extern "C" void kernel_launch(void* const* d_in, const int* in_sizes, int n_in,
                              void* d_out, int out_size, void* d_ws, size_t ws_size,
                              hipStream_t stream) {
  const float* x  = (const float*)d_in[0];
  const float* Wk = (const float*)d_in[1];
  const float* Wq = (const float*)d_in[2];
  const float* Wv = (const float*)d_in[3];
  const float* Wo = (const float*)d_in[4];
  const float* bo = (const float*)d_in[5];
  float* out = (float*)d_out;
  char* ws = (char*)d_ws;
  // ws layout (bytes): x_bf 67108864 | w_bf 3145728 | wout_bf 1048576 |
  // q 15728640 | k 15728640 | v 15728640 | att 15728640  => total 134217728
  unsigned short* xbf  = (unsigned short*)(ws);
  unsigned short* wbf  = (unsigned short*)(ws + 67108864);
  unsigned short* wobf = (unsigned short*)(ws + 70254592);
  unsigned short* qws  = (unsigned short*)(ws + 71303168);
  unsigned short* kws  = (unsigned short*)(ws + 87031808);
  unsigned short* vws  = (unsigned short*)(ws + 102760448);
  unsigned short* attw = (unsigned short*)(ws + 118489088);

  k_cvt<<<dim3(32768), dim3(256), 0, stream>>>(x, xbf, 8388608);
  k_cvt_w<<<dim3(1536), dim3(256), 0, stream>>>(Wq, Wk, Wv, wbf);
  k_cvt<<<dim3(512), dim3(256), 0, stream>>>(Wo, wobf, 131072);
  k_qkv<<<dim3(480, 3), dim3(256), 0, stream>>>(xbf, wbf, qws, kws, vws);
  k_attn<<<dim3(512, 4), dim3(256), 0, stream>>>(qws, kws, vws, attw);
  k_out<<<dim3(256, 8), dim3(256), 0, stream>>>(attw, wobf, bo, out);
}

// Round 3
// 372.258 us; speedup vs baseline: 1.2212x; 1.2212x over previous
//
#include <hip/hip_runtime.h>
#include <cstdint>
#include <cstddef>

typedef __attribute__((ext_vector_type(8))) short bf16x8;
typedef __attribute__((ext_vector_type(4))) float f32x4;

__device__ __forceinline__ unsigned short f2bf(float f) {
  union { float f; uint32_t u; } v; v.f = f;
  uint32_t r = v.u + 0x7fffu + ((v.u >> 16) & 1u);
  return (unsigned short)(r >> 16);
}
__device__ __forceinline__ float bf2f(unsigned short u) {
  union { uint32_t u; float f; } v; v.u = ((uint32_t)u) << 16;
  return v.f;
}

// Q/K/V/att per-head offsets (elements). Layout per head: [b][s][l][128].
// L = 64>>h, cumL = {0,64,96,112}, off = B*SEG*cumL*128 = 65536*cumL
__device__ __forceinline__ size_t head_off(int h) {
  return (size_t)65536 * ((h == 0) ? 0 : (h == 1) ? 64 : (h == 2) ? 96 : 112);
}

// ---------------- fp32 -> bf16 converts ----------------
__global__ void k_cvt(const float* __restrict__ src, unsigned short* __restrict__ dst, int n4) {
  int i = blockIdx.x * 256 + threadIdx.x;
  if (i < n4) {
    float4 f = ((const float4*)src)[i];
    ushort4 u;
    u.x = f2bf(f.x); u.y = f2bf(f.y); u.z = f2bf(f.z); u.w = f2bf(f.w);
    ((ushort4*)dst)[i] = u;
  }
}

// Concat per head: rows [0:128)=Wq, [128:256)=Wk, [256:384)=Wv  (row-major [j][e], e=1024)
__global__ void k_cvt_w(const float* __restrict__ Wq, const float* __restrict__ Wk,
                        const float* __restrict__ Wv, unsigned short* __restrict__ dst) {
  int row = blockIdx.x;              // h*384 + j, 1536 rows
  int h = row / 384, j = row % 384;
  const float* src = (j < 128) ? (Wq + (size_t)(h * 128 + j) * 1024)
                   : (j < 256) ? (Wk + (size_t)(h * 128 + j - 128) * 1024)
                               : (Wv + (size_t)(h * 128 + j - 256) * 1024);
  int e = threadIdx.x * 4;
  float4 f = *(const float4*)(src + e);
  ushort4 u;
  u.x = f2bf(f.x); u.y = f2bf(f.y); u.z = f2bf(f.z); u.w = f2bf(f.w);
  *(ushort4*)(dst + (size_t)row * 1024 + e) = u;
}

// ---------------- stage 1: QKV projection GEMM (unchanged) ----------------
__global__ __launch_bounds__(256) void k_qkv(
    const unsigned short* __restrict__ xbf,
    const unsigned short* __restrict__ wbf,
    unsigned short* __restrict__ qws,
    unsigned short* __restrict__ kws,
    unsigned short* __restrict__ vws) {
  int gx = blockIdx.x, gy = blockIdx.y;
  int h, base;
  if (gx < 256)      { h = 0; base = 0; }
  else if (gx < 384) { h = 1; base = 256; }
  else if (gx < 448) { h = 2; base = 384; }
  else               { h = 3; base = 448; }
  int L = 64 >> h, dil = 1 << h;
  int inner = gx - base;
  int b = inner >> (6 - h);
  int l = inner & (L - 1);
  const unsigned short* Abase = xbf + ((size_t)(b * 8192 + l * dil * 128)) * 1024;
  const unsigned short* Bbase = wbf + ((size_t)(h * 384 + gy * 128)) * 1024;

  __shared__ unsigned short As[128][72];
  __shared__ unsigned short Bs[128][72];

  int tid = threadIdx.x;
  int lane = tid & 63, wave = tid >> 6;
  int wm = wave >> 1, wn = wave & 1;
  int li = lane & 15, lk8 = (lane >> 4) << 3;

  f32x4 acc[4][4] = {};

  int sr = tid >> 1, sc = (tid & 1) * 32;
  const unsigned short* Ag = Abase + (size_t)sr * 1024 + sc;
  const unsigned short* Bg = Bbase + (size_t)sr * 1024 + sc;

  for (int kc = 0; kc < 1024; kc += 64) {
    bf16x8 av[4], bv[4];
#pragma unroll
    for (int i = 0; i < 4; ++i) {
      av[i] = *(const bf16x8*)(Ag + kc + i * 8);
      bv[i] = *(const bf16x8*)(Bg + kc + i * 8);
    }
    __syncthreads();
#pragma unroll
    for (int i = 0; i < 4; ++i) {
      *(bf16x8*)&As[sr][sc + i * 8] = av[i];
      *(bf16x8*)&Bs[sr][sc + i * 8] = bv[i];
    }
    __syncthreads();
#pragma unroll
    for (int kk = 0; kk < 2; ++kk) {
      int k0 = kk * 32 + lk8;
      bf16x8 af[4], bfv[4];
#pragma unroll
      for (int mf = 0; mf < 4; ++mf)
        af[mf] = *(const bf16x8*)&As[wm * 64 + mf * 16 + li][k0];
#pragma unroll
      for (int nf = 0; nf < 4; ++nf)
        bfv[nf] = *(const bf16x8*)&Bs[wn * 64 + nf * 16 + li][k0];
#pragma unroll
      for (int mf = 0; mf < 4; ++mf)
#pragma unroll
        for (int nf = 0; nf < 4; ++nf)
          acc[mf][nf] = __builtin_amdgcn_mfma_f32_16x16x32_bf16(af[mf], bfv[nf], acc[mf][nf], 0, 0, 0);
    }
  }
  unsigned short* dst = ((gy == 0) ? qws : (gy == 1) ? kws : vws) + head_off(h);
  int ib = (lane >> 4) * 4;
#pragma unroll
  for (int mf = 0; mf < 4; ++mf) {
#pragma unroll
    for (int nf = 0; nf < 4; ++nf) {
#pragma unroll
      for (int rg = 0; rg < 4; ++rg) {
        int s = wm * 64 + mf * 16 + ib + rg;
        int j = wn * 64 + nf * 16 + li;
        dst[((size_t)((b * 128 + s) * L + l)) * 128 + j] = f2bf(acc[mf][nf][rg]);
      }
    }
  }
}

// ---------------- stage 2: MFMA dilated attention ----------------
// Per block: 64 combined rows = (64/L) consecutive s-instances (contiguous in ws).
// S[n][m] = K·Q^T (MFMA, frags direct from global), mask: same-instance && lm<=ln,
// softmax over m per n (wave-parallel shfl butterfly), P^T -> LDS,
// att[m][v] = sum_n P^T[m][n] V^T[v][n] (MFMA, V transposed in LDS).
__global__ __launch_bounds__(256) void k_attn(
    const unsigned short* __restrict__ qws,
    const unsigned short* __restrict__ kws,
    const unsigned short* __restrict__ vws,
    unsigned short* __restrict__ att) {
  int bx = blockIdx.x;
  int h, inst;
  if (bx < 512)      { h = 0; inst = bx; }
  else if (bx < 768) { h = 1; inst = bx - 512; }
  else if (bx < 896) { h = 2; inst = bx - 768; }
  else               { h = 3; inst = bx - 896; }
  int lgL = 6 - h;
  int L = 64 >> h;
  int Lm1 = L - 1;
  int bpb = 128 >> h;                     // blocks per batch
  int b = inst / bpb;
  int s0 = (inst % bpb) << h;
  size_t off0 = head_off(h) + ((size_t)(b * 128 + s0) * L) * 128;  // contiguous 64x128
  const unsigned short* Qg = qws + off0;
  const unsigned short* Kg = kws + off0;
  const unsigned short* Vg = vws + off0;
  unsigned short* Og = att + off0;

  __shared__ unsigned short PT[64][72];     // P^T[m][n]
  __shared__ unsigned short VtL[128][72];   // V^T[v][n]

  int tid = threadIdx.x;
  int lane = tid & 63, w = tid >> 6;
  int li = lane & 15, q = lane >> 4;
  int lk8 = q << 3;

  // ---- stage V transposed into LDS (reads L2-resident, writes 2-way banks) ----
#pragma unroll
  for (int c = 0; c < 4; ++c) {
    int u = tid + c * 256;          // 1024 units of 8 elems
    int n = u & 63, vblk = u >> 6;  // lanes vary n fast -> ds writes conflict-light
    bf16x8 ve = *(const bf16x8*)(Vg + n * 128 + vblk * 8);
#pragma unroll
    for (int j = 0; j < 8; ++j)
      VtL[vblk * 8 + j][n] = (unsigned short)ve[j];
  }

  // ---- QK^T: wave w owns n-strip [16w,16w+16), m in [0,64) ----
  f32x4 sacc[4] = {};
  int nrow = 16 * w + li;
  for (int kc = 0; kc < 4; ++kc) {
    int d0 = kc * 32 + lk8;
    bf16x8 af = *(const bf16x8*)(Kg + nrow * 128 + d0);
#pragma unroll
    for (int mt = 0; mt < 4; ++mt) {
      bf16x8 bfq = *(const bf16x8*)(Qg + (mt * 16 + li) * 128 + d0);
      sacc[mt] = __builtin_amdgcn_mfma_f32_16x16x32_bf16(af, bfq, sacc[mt], 0, 0, 0);
    }
  }

  // ---- mask + scale; softmax over m per n (reg + shfl, all lanes busy) ----
  float sv[4][4];                     // [mt][reg]
#pragma unroll
  for (int mt = 0; mt < 4; ++mt)
#pragma unroll
    for (int r = 0; r < 4; ++r) {
      int n = 16 * w + 4 * q + r;
      int m = mt * 16 + li;
      bool valid = ((m >> lgL) == (n >> lgL)) && ((m & Lm1) <= (n & Lm1));
      sv[mt][r] = valid ? sacc[mt][r] * 0.08838834764831845f : -1e30f;
    }
  float inv[4];
#pragma unroll
  for (int r = 0; r < 4; ++r) {
    float m0 = fmaxf(fmaxf(sv[0][r], sv[1][r]), fmaxf(sv[2][r], sv[3][r]));
#pragma unroll
    for (int d = 1; d < 16; d <<= 1)
      m0 = fmaxf(m0, __shfl_xor(m0, d, 64));
    float s0 = 0.f;
#pragma unroll
    for (int mt = 0; mt < 4; ++mt) {
      sv[mt][r] = __expf(sv[mt][r] - m0);
      s0 += sv[mt][r];
    }
#pragma unroll
    for (int d = 1; d < 16; d <<= 1)
      s0 += __shfl_xor(s0, d, 64);
    inv[r] = 1.f / s0;
  }

  // ---- write P^T[m][n] (packed 4 consecutive n per lane) ----
#pragma unroll
  for (int mt = 0; mt < 4; ++mt) {
    ushort4 pk;
    pk.x = f2bf(sv[mt][0] * inv[0]);
    pk.y = f2bf(sv[mt][1] * inv[1]);
    pk.z = f2bf(sv[mt][2] * inv[2]);
    pk.w = f2bf(sv[mt][3] * inv[3]);
    *(ushort4*)&PT[mt * 16 + li][16 * w + 4 * q] = pk;
  }
  __syncthreads();

  // ---- PV: wave w owns m-strip [16w,16w+16), v in [0,128) ----
  f32x4 oacc[8] = {};
#pragma unroll
  for (int ks = 0; ks < 2; ++ks) {
    int n0 = ks * 32 + lk8;
    bf16x8 af = *(const bf16x8*)&PT[16 * w + li][n0];
#pragma unroll
    for (int vt = 0; vt < 8; ++vt) {
      bf16x8 bfv = *(const bf16x8*)&VtL[vt * 16 + li][n0];
      oacc[vt] = __builtin_amdgcn_mfma_f32_16x16x32_bf16(af, bfv, oacc[vt], 0, 0, 0);
    }
  }
#pragma unroll
  for (int vt = 0; vt < 8; ++vt) {
#pragma unroll
    for (int r = 0; r < 4; ++r) {
      int m = 16 * w + 4 * q + r;
      int v = vt * 16 + li;
      Og[m * 128 + v] = f2bf(oacc[vt][r]);
    }
  }
}

// ---------------- stage 3: gather + output projection GEMM (unchanged) ----------------
__global__ __launch_bounds__(256) void k_out(
    const unsigned short* __restrict__ att,
    const unsigned short* __restrict__ wout,
    const float* __restrict__ bout,
    float* __restrict__ out) {
  int mt = blockIdx.x, nt = blockIdx.y;
  int row0 = mt * 128;

  __shared__ unsigned short As[128][72];
  __shared__ unsigned short Bs[128][72];

  int tid = threadIdx.x;
  int lane = tid & 63, wave = tid >> 6;
  int wm = wave >> 1, wn = wave & 1;
  int li = lane & 15, lk8 = (lane >> 4) << 3;

  f32x4 acc[4][4] = {};

  int sr = tid >> 1, sc = (tid & 1) * 32;
  int rowg = row0 + sr;
  int b = rowg >> 13, t = rowg & 8191;
  const unsigned short* Bg = wout + (size_t)(nt * 128 + sr) * 512 + sc;
  const bf16x8 ZV = {0, 0, 0, 0, 0, 0, 0, 0};

  for (int kc = 0; kc < 512; kc += 64) {
    int c0 = kc + sc;
    int hd = c0 >> 7, v0 = c0 & 127;
    int dil = 1 << hd, Lh = 64 >> hd;
    bf16x8 av[4], bv[4];
    if ((t & (dil - 1)) == 0) {
      int j = t >> hd;
      int s = j >> (6 - hd), l = j & (Lh - 1);
      const unsigned short* Ag = att + head_off(hd)
          + ((size_t)((b * 128 + s) * Lh + l)) * 128 + v0;
#pragma unroll
      for (int i = 0; i < 4; ++i) av[i] = *(const bf16x8*)(Ag + i * 8);
    } else {
#pragma unroll
      for (int i = 0; i < 4; ++i) av[i] = ZV;
    }
#pragma unroll
    for (int i = 0; i < 4; ++i) bv[i] = *(const bf16x8*)(Bg + kc + i * 8);
    __syncthreads();
#pragma unroll
    for (int i = 0; i < 4; ++i) {
      *(bf16x8*)&As[sr][sc + i * 8] = av[i];
      *(bf16x8*)&Bs[sr][sc + i * 8] = bv[i];
    }
    __syncthreads();
#pragma unroll
    for (int kk = 0; kk < 2; ++kk) {
      int k0 = kk * 32 + lk8;
      bf16x8 af[4], bfv[4];
#pragma unroll
      for (int mf = 0; mf < 4; ++mf)
        af[mf] = *(const bf16x8*)&As[wm * 64 + mf * 16 + li][k0];
#pragma unroll
      for (int nf = 0; nf < 4; ++nf)
        bfv[nf] = *(const bf16x8*)&Bs[wn * 64 + nf * 16 + li][k0];
#pragma unroll
      for (int mf = 0; mf < 4; ++mf)
#pragma unroll
        for (int nf = 0; nf < 4; ++nf)
          acc[mf][nf] = __builtin_amdgcn_mfma_f32_16x16x32_bf16(af[mf], bfv[nf], acc[mf][nf], 0, 0, 0);
    }
  }
  int ib = (lane >> 4) * 4;
#pragma unroll
  for (int mf = 0; mf < 4; ++mf) {
#pragma unroll
    for (int nf = 0; nf < 4; ++nf) {
      int col = nt * 128 + wn * 64 + nf * 16 + li;
      float bo = bout[col];
#pragma unroll
      for (int rg = 0; rg < 4; ++rg) {
        int r = row0 + wm * 64 + mf * 16 + ib + rg;
        out[(size_t)r * 1024 + col] = acc[mf][nf][rg] + bo;
      }
    }
  }
}

extern "C" void kernel_launch(void* const* d_in, const int* in_sizes, int n_in,
                              void* d_out, int out_size, void* d_ws, size_t ws_size,
                              hipStream_t stream) {
  const float* x  = (const float*)d_in[0];
  const float* Wk = (const float*)d_in[1];
  const float* Wq = (const float*)d_in[2];
  const float* Wv = (const float*)d_in[3];
  const float* Wo = (const float*)d_in[4];
  const float* bo = (const float*)d_in[5];
  float* out = (float*)d_out;
  char* ws = (char*)d_ws;
  unsigned short* xbf  = (unsigned short*)(ws);
  unsigned short* wbf  = (unsigned short*)(ws + 67108864);
  unsigned short* wobf = (unsigned short*)(ws + 70254592);
  unsigned short* qws  = (unsigned short*)(ws + 71303168);
  unsigned short* kws  = (unsigned short*)(ws + 87031808);
  unsigned short* vws  = (unsigned short*)(ws + 102760448);
  unsigned short* attw = (unsigned short*)(ws + 118489088);

  k_cvt<<<dim3(32768), dim3(256), 0, stream>>>(x, xbf, 8388608);
  k_cvt_w<<<dim3(1536), dim3(256), 0, stream>>>(Wq, Wk, Wv, wbf);
  k_cvt<<<dim3(512), dim3(256), 0, stream>>>(Wo, wobf, 131072);
  k_qkv<<<dim3(480, 3), dim3(256), 0, stream>>>(xbf, wbf, qws, kws, vws);
  k_attn<<<dim3(960), dim3(256), 0, stream>>>(qws, kws, vws, attw);
  k_out<<<dim3(256, 8), dim3(256), 0, stream>>>(attw, wobf, bo, out);
}